// Round 1
// baseline (2092.900 us; speedup 1.0000x reference)
//
#include <hip/hip_runtime.h>

#define BB 4
#define CC 256
#define NN 16384
#define DD 64
#define NH 8
#define DK 512
#define QSCALE 0.35355339059327373f
#define EPSV 1e-5f
#define GRPN 524288.0f   // 32 channels * 16384 spatial per group

// ws layout (floats)
#define CTX_OFF  0        // [B][NH][64][64] = 131072
#define KSUM_OFF 131072   // [B][NH][64]     = 2048
#define GSUM_OFF 133120   // [B][16]
#define GSQ_OFF  133184   // [B][16]
#define WS_ZERO_FLOATS 133248

// ---------------------------------------------------------------------------
// K1: fused kv projection + exp(k*scale) + ksum + ctx accumulation
// grid (32 n-chunks, NH, B), 256 threads. chunk = 512 cols, 8 subtiles of 64.
// ---------------------------------------------------------------------------
__global__ __launch_bounds__(256, 2) void k1_kv_ctx(
    const float* __restrict__ x, const float* __restrict__ wkv, float* ws) {
  const int t = threadIdx.x;
  const int h = blockIdx.y, b = blockIdx.z;
  const int nbase = blockIdx.x * 512;

  __shared__ __align__(16) float xt[32][68];  // x K-tile, stride mult-of-16B for float4
  __shared__ float kv[128][65];               // k rows 0..63 (-> exp'd), v rows 64..127
  __shared__ float red[64][4];

  const int ty = t >> 3;        // 0..31 -> output rows ty*4..+3
  const int tx = t & 7;         // cols tx*8..+7
  const int r0 = ty * 4;
  const int grow = (r0 < 64) ? (h * 64 + r0) : (512 + h * 64 + (r0 - 64));
  const float* wr = wkv + (size_t)grow * 256;
  const float* xb = x + (size_t)b * CC * NN;

  const int dd = t & 63;        // exp/ctx row
  const int qq = t >> 6;        // 0..3 (== wave id)
  const int e0 = qq * 16;

  float ctx_acc[16];
  #pragma unroll
  for (int i = 0; i < 16; ++i) ctx_acc[i] = 0.f;
  float ksum_part = 0.f;

  for (int st = 0; st < 8; ++st) {
    const int n0 = nbase + st * 64;
    float acc[4][8];
    #pragma unroll
    for (int r = 0; r < 4; ++r)
      #pragma unroll
      for (int j = 0; j < 8; ++j) acc[r][j] = 0.f;

    for (int kt = 0; kt < 8; ++kt) {
      __syncthreads();   // guard xt overwrite vs previous readers
      {
        const int j4 = (t & 15) * 4;
        #pragma unroll
        for (int i = 0; i < 2; ++i) {
          const int cc2 = (t >> 4) + i * 16;
          *(float4*)&xt[cc2][j4] =
              *(const float4*)(xb + (size_t)(kt * 32 + cc2) * NN + n0 + j4);
        }
      }
      __syncthreads();
      #pragma unroll 4
      for (int kk = 0; kk < 32; ++kk) {
        const int c = kt * 32 + kk;
        const float w0 = wr[c];
        const float w1 = wr[256 + c];
        const float w2 = wr[512 + c];
        const float w3 = wr[768 + c];
        const float4* xp = (const float4*)&xt[kk][tx * 8];
        const float4 a0 = xp[0], a1 = xp[1];
        const float xv[8] = {a0.x, a0.y, a0.z, a0.w, a1.x, a1.y, a1.z, a1.w};
        #pragma unroll
        for (int j = 0; j < 8; ++j) {
          acc[0][j] += w0 * xv[j];
          acc[1][j] += w1 * xv[j];
          acc[2][j] += w2 * xv[j];
          acc[3][j] += w3 * xv[j];
        }
      }
    }
    #pragma unroll
    for (int r = 0; r < 4; ++r)
      #pragma unroll
      for (int j = 0; j < 8; ++j)
        kv[r0 + r][tx * 8 + j] = acc[r][j];
    __syncthreads();
    // exp on k rows; accumulate row-sum partials
    {
      float ls = 0.f;
      #pragma unroll
      for (int j = 0; j < 16; ++j) {
        const float e = __expf(kv[dd][e0 + j] * QSCALE);
        kv[dd][e0 + j] = e;
        ls += e;
      }
      ksum_part += ls;
    }
    __syncthreads();
    // ctx[dd][e0+ee] += sum_j exp_k[dd][j] * v[e0+ee][j]
    for (int j = 0; j < 64; ++j) {
      const float sv = kv[dd][j];
      #pragma unroll
      for (int ee = 0; ee < 16; ++ee)
        ctx_acc[ee] += sv * kv[64 + e0 + ee][j];
    }
    // next kv write is >=2 barriers away (kt-loop syncs) -> safe
  }

  red[dd][qq] = ksum_part;
  __syncthreads();
  if (t < 64) {
    const float s = red[t][0] + red[t][1] + red[t][2] + red[t][3];
    atomicAdd(&ws[KSUM_OFF + (b * NH + h) * 64 + t], s);
  }
  float* ctxp = ws + CTX_OFF + (size_t)(b * NH + h) * 4096 + dd * 64 + e0;
  #pragma unroll
  for (int ee = 0; ee < 16; ++ee)
    atomicAdd(ctxp + ee, ctx_acc[ee]);
}

// ---------------------------------------------------------------------------
// Kx: GroupNorm stats for groups 8..15 (the x half of the concat)
// grid (64, 8, B), 256 threads; block covers 32 channels x 256 cols
// ---------------------------------------------------------------------------
__global__ __launch_bounds__(256) void k_xstats(const float* __restrict__ x, float* ws) {
  const int t = threadIdx.x;
  const int b = blockIdx.z, g = blockIdx.y;
  const int n0 = blockIdx.x * 256;
  const float* xb = x + ((size_t)b * CC + g * 32) * NN + n0;
  const int cc0 = t >> 6;           // 0..3
  const int j4 = (t & 63) * 4;
  float s = 0.f, s2 = 0.f;
  #pragma unroll
  for (int i = 0; i < 8; ++i) {
    const float4 v = *(const float4*)(xb + (size_t)(cc0 + i * 4) * NN + j4);
    s += v.x + v.y + v.z + v.w;
    s2 += v.x * v.x + v.y * v.y + v.z * v.z + v.w * v.w;
  }
  #pragma unroll
  for (int m = 1; m <= 32; m <<= 1) {
    s += __shfl_xor(s, m);
    s2 += __shfl_xor(s2, m);
  }
  __shared__ float rs[4], rs2[4];
  if ((t & 63) == 0) { rs[t >> 6] = s; rs2[t >> 6] = s2; }
  __syncthreads();
  if (t == 0) {
    atomicAdd(&ws[GSUM_OFF + b * 16 + 8 + g], rs[0] + rs[1] + rs[2] + rs[3]);
    atomicAdd(&ws[GSQ_OFF + b * 16 + 8 + g], rs2[0] + rs2[1] + rs2[2] + rs2[3]);
  }
}

// ---------------------------------------------------------------------------
// K2: q projection + softmax_d + (ctx/ksum) apply + out projection + bias
//     + GroupNorm partial sums (groups 0..7). Writes pre-norm to out ch 0..255.
// grid (256 n-tiles, B), 512 threads, dynamic LDS ~118KB
// ---------------------------------------------------------------------------
__global__ __launch_bounds__(512, 2) void k2_q_attn_proj(
    const float* __restrict__ x, const float* __restrict__ wq,
    const float* __restrict__ wo, const float* __restrict__ bo,
    float* ws, float* __restrict__ out) {
  extern __shared__ __align__(16) float sm[];
  float (*xs)[68]   = (float(*)[68])sm;                          // 256x68
  float (*pa)[68]   = (float(*)[68])(sm + 17408);                // 64x68 (q -> p)
  float (*obuf)[68] = (float(*)[68])(sm + 17408 + 4352);         // 64x68 (attn out)
  float (*ctxs)[64] = (float(*)[64])(sm + 17408 + 8704);         // 64x64
  float* ksinv      = sm + 17408 + 8704 + 4096;                  // 64

  const int t = threadIdx.x;
  const int b = blockIdx.y;
  const int n0 = blockIdx.x * 64;

  // stage x strip [256 c][64 n]
  {
    const int j4 = (t & 15) * 4;
    const int c0 = t >> 4;            // 0..31
    #pragma unroll
    for (int i = 0; i < 8; ++i) {
      const int c = c0 + i * 32;
      *(float4*)&xs[c][j4] = *(const float4*)(x + ((size_t)b * CC + c) * NN + n0 + j4);
    }
  }

  float yo[32];
  #pragma unroll
  for (int i = 0; i < 32; ++i) yo[i] = 0.f;

  const int qd = t >> 3;          // 0..63 (q row / softmax col / attn e-row)
  const int jq = (t & 7) * 8;     // 8-col slice
  const int part = (t & 7) * 8;   // softmax d-slice
  const int orow = t >> 1;        // 0..255 output channel
  const int jhalf = (t & 1) * 32;

  for (int h = 0; h < NH; ++h) {
    __syncthreads();
    if (t < 64) ksinv[t] = 1.f / ws[KSUM_OFF + (b * NH + h) * 64 + t];
    __syncthreads();
    {
      const float* cg = ws + CTX_OFF + (size_t)(b * NH + h) * 4096;
      #pragma unroll
      for (int i = 0; i < 8; ++i) {
        const int l = t + i * 512;
        ctxs[l >> 6][l & 63] = cg[l] * ksinv[l >> 6];
      }
    }
    // q GEMM: q[qd][jq..+7]
    float qa[8];
    #pragma unroll
    for (int i = 0; i < 8; ++i) qa[i] = 0.f;
    {
      const float* wrow = wq + (size_t)(h * 64 + qd) * 256;
      #pragma unroll 4
      for (int c = 0; c < 256; ++c) {
        const float wv = wrow[c];
        const float4* xp = (const float4*)&xs[c][jq];
        const float4 a0 = xp[0], a1 = xp[1];
        qa[0] += wv * a0.x; qa[1] += wv * a0.y; qa[2] += wv * a0.z; qa[3] += wv * a0.w;
        qa[4] += wv * a1.x; qa[5] += wv * a1.y; qa[6] += wv * a1.z; qa[7] += wv * a1.w;
      }
    }
    __syncthreads();
    #pragma unroll
    for (int i = 0; i < 8; ++i) pa[qd][jq + i] = qa[i];
    __syncthreads();
    // softmax over d per column: thread handles rows part..part+7 of column qd
    {
      float sv[8];
      float m = -1e30f;
      #pragma unroll
      for (int i = 0; i < 8; ++i) { sv[i] = pa[part + i][qd] * QSCALE; m = fmaxf(m, sv[i]); }
      m = fmaxf(m, __shfl_xor(m, 1));
      m = fmaxf(m, __shfl_xor(m, 2));
      m = fmaxf(m, __shfl_xor(m, 4));
      float se = 0.f;
      #pragma unroll
      for (int i = 0; i < 8; ++i) { sv[i] = __expf(sv[i] - m); se += sv[i]; }
      se += __shfl_xor(se, 1); se += __shfl_xor(se, 2); se += __shfl_xor(se, 4);
      const float inv = 1.f / se;
      #pragma unroll
      for (int i = 0; i < 8; ++i) pa[part + i][qd] = sv[i] * inv;
    }
    __syncthreads();
    // attn out: ob[qd][jq..+7] = sum_d ctxs[d][qd] * p[d][jq..+7]
    float oa[8];
    #pragma unroll
    for (int i = 0; i < 8; ++i) oa[i] = 0.f;
    for (int d = 0; d < 64; ++d) {
      const float cv = ctxs[d][qd];
      const float4* pp = (const float4*)&pa[d][jq];
      const float4 p0 = pp[0], p1 = pp[1];
      oa[0] += cv * p0.x; oa[1] += cv * p0.y; oa[2] += cv * p0.z; oa[3] += cv * p0.w;
      oa[4] += cv * p1.x; oa[5] += cv * p1.y; oa[6] += cv * p1.z; oa[7] += cv * p1.w;
    }
    __syncthreads();     // guard obuf overwrite vs previous proj reads
    #pragma unroll
    for (int i = 0; i < 8; ++i) obuf[qd][jq + i] = oa[i];
    __syncthreads();
    // out projection accumulate: yo[orow][jhalf..+31] += wo[orow][h*64+e]*ob[e][:]
    {
      const float* worow = wo + (size_t)orow * DK + h * 64;
      #pragma unroll 2
      for (int e = 0; e < 64; ++e) {
        const float wv = worow[e];
        const float4* op = (const float4*)&obuf[e][jhalf];
        #pragma unroll
        for (int i = 0; i < 8; ++i) {
          const float4 ov = op[i];
          yo[i * 4 + 0] += wv * ov.x;
          yo[i * 4 + 1] += wv * ov.y;
          yo[i * 4 + 2] += wv * ov.z;
          yo[i * 4 + 3] += wv * ov.w;
        }
      }
    }
  }
  // bias + group partial sums (wave w covers exactly group w rows 32w..32w+31)
  const float bv = bo[orow];
  float s = 0.f, s2 = 0.f;
  #pragma unroll
  for (int i = 0; i < 32; ++i) {
    yo[i] += bv;
    s += yo[i];
    s2 += yo[i] * yo[i];
  }
  #pragma unroll
  for (int m = 1; m <= 32; m <<= 1) { s += __shfl_xor(s, m); s2 += __shfl_xor(s2, m); }
  if ((t & 63) == 0) {
    const int g = orow >> 5;
    atomicAdd(&ws[GSUM_OFF + b * 16 + g], s);
    atomicAdd(&ws[GSQ_OFF + b * 16 + g], s2);
  }
  // stage yo through LDS (reuse xs) for coalesced n-major store
  __syncthreads();
  #pragma unroll
  for (int i = 0; i < 8; ++i)
    *(float4*)&xs[orow][jhalf + i * 4] =
        make_float4(yo[i * 4 + 0], yo[i * 4 + 1], yo[i * 4 + 2], yo[i * 4 + 3]);
  __syncthreads();
  {
    const int j4 = (t & 15) * 4;
    const int oo = t >> 4;       // 0..31
    #pragma unroll
    for (int i = 0; i < 8; ++i) {
      const int row = oo + i * 32;
      const float4 v = *(const float4*)&xs[row][j4];
      *(float4*)(out + ((size_t)b * 512 + row) * NN + n0 + j4) = v;
    }
  }
}

// ---------------------------------------------------------------------------
// K3: GroupNorm finalize. ch<256: normalize out in place; ch>=256: from x.
// grid (16, 512, B), 256 threads, float4 per thread
// ---------------------------------------------------------------------------
__global__ __launch_bounds__(256) void k3_groupnorm(
    const float* __restrict__ x, const float* __restrict__ gamma,
    const float* __restrict__ beta, const float* __restrict__ ws,
    float* out) {
  const int t = threadIdx.x;
  const int b = blockIdx.z, ch = blockIdx.y;
  const int n0 = blockIdx.x * 1024 + t * 4;
  const int g = ch >> 5;
  const float s = ws[GSUM_OFF + b * 16 + g];
  const float s2 = ws[GSQ_OFF + b * 16 + g];
  const float mean = s / GRPN;
  const float var = s2 / GRPN - mean * mean;
  const float inv = rsqrtf(var + EPSV);
  const float ga = gamma[ch] * inv;
  const float be = beta[ch] - mean * ga;
  float* op = out + ((size_t)b * 512 + ch) * NN + n0;
  float4 v;
  if (ch < 256) v = *(const float4*)op;
  else v = *(const float4*)(x + ((size_t)b * CC + (ch - 256)) * NN + n0);
  v.x = v.x * ga + be;
  v.y = v.y * ga + be;
  v.z = v.z * ga + be;
  v.w = v.w * ga + be;
  *(float4*)op = v;
}

extern "C" void kernel_launch(void* const* d_in, const int* in_sizes, int n_in,
                              void* d_out, int out_size, void* d_ws, size_t ws_size,
                              hipStream_t stream) {
  const float* x     = (const float*)d_in[0];
  const float* wq    = (const float*)d_in[1];
  const float* wkv   = (const float*)d_in[2];
  const float* wo    = (const float*)d_in[3];
  const float* bo    = (const float*)d_in[4];
  const float* gamma = (const float*)d_in[5];
  const float* beta  = (const float*)d_in[6];
  float* out = (float*)d_out;
  float* ws = (float*)d_ws;

  hipMemsetAsync(ws, 0, WS_ZERO_FLOATS * sizeof(float), stream);
  k1_kv_ctx<<<dim3(32, NH, BB), 256, 0, stream>>>(x, wkv, ws);
  k_xstats<<<dim3(64, 8, BB), 256, 0, stream>>>(x, ws);
  const int k2_smem = (17408 + 4352 + 4352 + 4096 + 64) * 4;
  k2_q_attn_proj<<<dim3(256, BB), 512, k2_smem, stream>>>(x, wq, wo, bo, ws, out);
  k3_groupnorm<<<dim3(16, 512, BB), 256, 0, stream>>>(x, gamma, beta, ws, out);
}

// Round 2
// 344.350 us; speedup vs baseline: 6.0778x; 6.0778x over previous
//
#include <hip/hip_runtime.h>

typedef int    i32x4 __attribute__((ext_vector_type(4)));
typedef float  f32x4 __attribute__((ext_vector_type(4)));
typedef __bf16 bf16x8 __attribute__((ext_vector_type(8)));
union B16 { i32x4 i; bf16x8 v; };

#define NN 16384
#define QSCALE 0.35355339059327373f
#define EPSV 1e-5f
#define GRPN 524288.0f

// ws layout (floats) — only the atomic-accumulator region lives in ws.
#define CTX_OFF  0        // [4][8][64][64]
#define KSUM_OFF 131072   // [4][8][64]
#define GSUM_OFF 133120   // [4][16]
#define GSQ_OFF  133184   // [4][16]
#define WS_ZERO_FLOATS 133248

// Big scratch (xT bf16 + bf16 weights + weff) lives in d_out channels 256-511,
// which k3 overwrites last. xT[b] sits at out+(b*512+256)*NN; weights after
// xT[0] inside batch-0's spare region.

__device__ __forceinline__ ushort f2bfu(float f) {
  union { __bf16 h; ushort u; } c; c.h = (__bf16)f; return c.u;
}
__device__ __forceinline__ uint packbf2(float lo, float hi) {
  return (uint)f2bfu(lo) | ((uint)f2bfu(hi) << 16);
}

// ---------------------------------------------------------------------------
// k_cvt: fp32 -> bf16 weight conversion
// ---------------------------------------------------------------------------
__global__ __launch_bounds__(256) void k_cvt(const float* __restrict__ s,
                                             ushort* __restrict__ d, int n) {
  int i = (blockIdx.x * 256 + threadIdx.x) * 4;
  if (i >= n) return;
  float4 v = *(const float4*)(s + i);
  uint2 p; p.x = packbf2(v.x, v.y); p.y = packbf2(v.z, v.w);
  *(uint2*)(d + i) = p;
}

// ---------------------------------------------------------------------------
// k0: x[b][c][n] f32 -> xT[b][n][c] bf16 (transpose via LDS) + group stats 8-15
// grid (256 ntiles, 8 cgroups, 4 b), 256 thr. Tile = 32 c x 64 n.
// ---------------------------------------------------------------------------
__global__ __launch_bounds__(256) void k0_xprep(const float* __restrict__ x,
                                                float* __restrict__ outp,
                                                float* ws) {
  const int t = threadIdx.x;
  const int n0 = blockIdx.x * 64, cg = blockIdx.y, b = blockIdx.z;
  __shared__ __align__(16) uint tile[64 * 17];
  const int c = t >> 3;           // local channel 0..31
  const int nb = (t & 7) * 8;     // n offset 0..56
  const float* src = x + ((size_t)(b * 256 + cg * 32 + c)) * NN + n0 + nb;
  float v[8];
  { float4 a0 = *(const float4*)src; float4 a1 = *(const float4*)(src + 4);
    v[0]=a0.x; v[1]=a0.y; v[2]=a0.z; v[3]=a0.w; v[4]=a1.x; v[5]=a1.y; v[6]=a1.z; v[7]=a1.w; }
  float s = 0.f, s2 = 0.f;
  #pragma unroll
  for (int j = 0; j < 8; ++j) { s += v[j]; s2 += v[j] * v[j]; }
  // exchange with channel-partner (c^1) lane, pack bf16 pairs, write [n][cpair]
  float th[8];
  #pragma unroll
  for (int j = 0; j < 8; ++j) th[j] = __shfl_xor(v[j], 8);
  const bool even = ((t >> 3) & 1) == 0;
  const int cp = t >> 4;          // local cpair 0..15
  #pragma unroll
  for (int jj = 0; jj < 4; ++jj) {
    const int j = even ? jj : (4 + jj);
    const float lo = even ? v[j] : th[j];
    const float hi = even ? th[j] : v[j];
    tile[(nb + j) * 17 + cp] = packbf2(lo, hi);
  }
  __syncthreads();
  {
    const int n = t >> 2, co = (t & 3) * 4;
    uint o0 = tile[n*17+co], o1 = tile[n*17+co+1], o2 = tile[n*17+co+2], o3 = tile[n*17+co+3];
    ushort* xT = (ushort*)(outp + ((size_t)(b * 512 + 256)) * NN);
    ushort* dst = xT + (size_t)(n0 + n) * 256 + cg * 32 + (t & 3) * 8;
    i32x4 pk; pk[0] = (int)o0; pk[1] = (int)o1; pk[2] = (int)o2; pk[3] = (int)o3;
    *(i32x4*)dst = pk;
  }
  #pragma unroll
  for (int m = 1; m <= 32; m <<= 1) { s += __shfl_xor(s, m); s2 += __shfl_xor(s2, m); }
  __shared__ float rs[4], rq[4];
  const int w = t >> 6;
  if ((t & 63) == 0) { rs[w] = s; rq[w] = s2; }
  __syncthreads();
  if (t == 0) {
    atomicAdd(&ws[GSUM_OFF + b * 16 + 8 + cg], rs[0] + rs[1] + rs[2] + rs[3]);
    atomicAdd(&ws[GSQ_OFF  + b * 16 + 8 + cg], rq[0] + rq[1] + rq[2] + rq[3]);
  }
}

// ---------------------------------------------------------------------------
// k1: MFMA kv-proj + exp(k) + ksum + ctx = Kexp @ V^T  (per b,h, 512-n chunk)
// grid (32, 8, 4), 256 thr (4 waves). LDS: swizzled x-tile + f32 K/V bufs.
// ---------------------------------------------------------------------------
__global__ __launch_bounds__(256, 2) void k1_kvctx(const float* __restrict__ outp,
                                                   const ushort* __restrict__ wkv_bf,
                                                   float* ws) {
  const int t = threadIdx.x, lane = t & 63, w = t >> 6;
  const int l15 = lane & 15, l4 = lane >> 4;
  const int chunk = blockIdx.x, h = blockIdx.y, b = blockIdx.z;
  const ushort* xT = (const ushort*)(outp + ((size_t)(b * 512 + 256)) * NN);
  __shared__ __align__(16) ushort xt[64 * 256];   // [n][c] bf16, slot-swizzled
  __shared__ __align__(16) float Kb[64 * 68];     // exp'd K [d][n]
  __shared__ __align__(16) float Vb[64 * 68];     // V [e][n]

  // preload wkv A-fragments (wave w: rows 32w..32w+31 of the 128-row head slice)
  const int rbase = (w < 2) ? (h * 64 + 32 * w) : (512 + h * 64 + 32 * (w - 2));
  B16 afr[2][8];
  #pragma unroll
  for (int m = 0; m < 2; ++m) {
    const ushort* wr = wkv_bf + (size_t)(rbase + 16 * m + l15) * 256 + l4 * 8;
    #pragma unroll
    for (int ks = 0; ks < 8; ++ks) afr[m][ks].i = *(const i32x4*)(wr + ks * 32);
  }

  f32x4 ctxc[4];
  #pragma unroll
  for (int ct = 0; ct < 4; ++ct) ctxc[ct] = f32x4{0.f, 0.f, 0.f, 0.f};
  float ksp[2][4] = {};

  for (int st = 0; st < 8; ++st) {
    const int n0 = chunk * 512 + st * 64;
    {  // stage x tile, swizzled (slot ^= n&31)
      const int n = t >> 2;
      const ushort* srcp = xT + (size_t)(n0 + n) * 256 + (t & 3) * 64;
      #pragma unroll
      for (int i = 0; i < 8; ++i) {
        const int slot = ((t & 3) * 8 + i) ^ (n & 31);
        *(i32x4*)((char*)xt + n * 512 + slot * 16) = *(const i32x4*)(srcp + i * 8);
      }
    }
    __syncthreads();
    f32x4 acc[2][4];
    #pragma unroll
    for (int m = 0; m < 2; ++m)
      #pragma unroll
      for (int ct = 0; ct < 4; ++ct) acc[m][ct] = f32x4{0.f, 0.f, 0.f, 0.f};
    #pragma unroll 2
    for (int ks = 0; ks < 8; ++ks) {
      B16 bfr[4];
      #pragma unroll
      for (int ct = 0; ct < 4; ++ct) {
        const int n = ct * 16 + l15;
        const int slot = (ks * 4 + l4) ^ (n & 31);
        bfr[ct].i = *(const i32x4*)((const char*)xt + n * 512 + slot * 16);
      }
      #pragma unroll
      for (int m = 0; m < 2; ++m)
        #pragma unroll
        for (int ct = 0; ct < 4; ++ct)
          acc[m][ct] = __builtin_amdgcn_mfma_f32_16x16x32_bf16(afr[m][ks].v, bfr[ct].v, acc[m][ct], 0, 0, 0);
    }
    // K rows: exp + ksum partials; V rows: raw. acc row = l4*4+r, col = ct*16+l15
    if (w < 2) {
      #pragma unroll
      for (int m = 0; m < 2; ++m) {
        const int d = 32 * w + 16 * m + l4 * 4;
        #pragma unroll
        for (int ct = 0; ct < 4; ++ct)
          #pragma unroll
          for (int r = 0; r < 4; ++r) {
            const float e = __expf(acc[m][ct][r] * QSCALE);
            ksp[m][r] += e;
            Kb[(d + r) * 68 + ct * 16 + l15] = e;
          }
      }
    } else {
      #pragma unroll
      for (int m = 0; m < 2; ++m) {
        const int ev = 32 * (w - 2) + 16 * m + l4 * 4;
        #pragma unroll
        for (int ct = 0; ct < 4; ++ct)
          #pragma unroll
          for (int r = 0; r < 4; ++r)
            Vb[(ev + r) * 68 + ct * 16 + l15] = acc[m][ct][r];
      }
    }
    __syncthreads();
    // ctx GEMM: ctx[d][e] += Kexp[d][n] * V[e][n]; wave w: d rows 16w..16w+15
    #pragma unroll
    for (int ks = 0; ks < 2; ++ks) {
      const float* ap = &Kb[(16 * w + l15) * 68 + ks * 32 + l4 * 8];
      f32x4 a0 = *(const f32x4*)ap, a1 = *(const f32x4*)(ap + 4);
      B16 af;
      #pragma unroll
      for (int j = 0; j < 4; ++j) { af.v[j] = (__bf16)a0[j]; af.v[4 + j] = (__bf16)a1[j]; }
      #pragma unroll
      for (int ct = 0; ct < 4; ++ct) {
        const float* bp = &Vb[(ct * 16 + l15) * 68 + ks * 32 + l4 * 8];
        f32x4 b0 = *(const f32x4*)bp, b1 = *(const f32x4*)(bp + 4);
        B16 bf2;
        #pragma unroll
        for (int j = 0; j < 4; ++j) { bf2.v[j] = (__bf16)b0[j]; bf2.v[4 + j] = (__bf16)b1[j]; }
        ctxc[ct] = __builtin_amdgcn_mfma_f32_16x16x32_bf16(af.v, bf2.v, ctxc[ct], 0, 0, 0);
      }
    }
    __syncthreads();
  }
  // epilogue: ksum + ctx atomics
  if (w < 2) {
    #pragma unroll
    for (int m = 0; m < 2; ++m)
      #pragma unroll
      for (int r = 0; r < 4; ++r) {
        float s = ksp[m][r];
        s += __shfl_xor(s, 1); s += __shfl_xor(s, 2);
        s += __shfl_xor(s, 4); s += __shfl_xor(s, 8);
        if (l15 == 0)
          atomicAdd(&ws[KSUM_OFF + (b * 8 + h) * 64 + 32 * w + 16 * m + l4 * 4 + r], s);
      }
  }
  float* cp = ws + CTX_OFF + (size_t)(b * 8 + h) * 4096;
  #pragma unroll
  for (int ct = 0; ct < 4; ++ct)
    #pragma unroll
    for (int r = 0; r < 4; ++r)
      atomicAdd(&cp[(16 * w + l4 * 4 + r) * 64 + ct * 16 + l15], ctxc[ct][r]);
}

// ---------------------------------------------------------------------------
// k1b: weff[b][o][h*64+d] = sum_e wo[o][h*64+e] * ctx[b,h][d][e] / ksum[b,h][d]
// grid (8 h, 4 b), 256 thr. Tiny MFMA GEMM M=256,N=64,K=64.
// ---------------------------------------------------------------------------
__global__ __launch_bounds__(256) void k1b_weff(const float* __restrict__ ws,
                                                const ushort* __restrict__ wo_bf,
                                                ushort* __restrict__ weff_bf) {
  const int t = threadIdx.x, lane = t & 63, w = t >> 6;
  const int l15 = lane & 15, l4 = lane >> 4;
  const int h = blockIdx.x, b = blockIdx.y;
  __shared__ float ksinv[64];
  if (t < 64) ksinv[t] = 1.f / ws[KSUM_OFF + (b * 8 + h) * 64 + t];
  __syncthreads();
  const float* ctxg = ws + CTX_OFF + (size_t)(b * 8 + h) * 4096;
  f32x4 acc[4][4];
  #pragma unroll
  for (int m = 0; m < 4; ++m)
    #pragma unroll
    for (int ct = 0; ct < 4; ++ct) acc[m][ct] = f32x4{0.f, 0.f, 0.f, 0.f};
  #pragma unroll
  for (int ks = 0; ks < 2; ++ks) {
    B16 bfr[4];
    #pragma unroll
    for (int ct = 0; ct < 4; ++ct) {
      const int d = ct * 16 + l15;
      const float inv = ksinv[d];
      const float* bp = ctxg + d * 64 + ks * 32 + l4 * 8;
      f32x4 b0 = *(const f32x4*)bp, b1 = *(const f32x4*)(bp + 4);
      #pragma unroll
      for (int j = 0; j < 4; ++j) {
        bfr[ct].v[j] = (__bf16)(b0[j] * inv);
        bfr[ct].v[4 + j] = (__bf16)(b1[j] * inv);
      }
    }
    #pragma unroll
    for (int m = 0; m < 4; ++m) {
      B16 af;
      af.i = *(const i32x4*)(wo_bf + (size_t)(w * 64 + m * 16 + l15) * 512 + h * 64 + ks * 32 + l4 * 8);
      #pragma unroll
      for (int ct = 0; ct < 4; ++ct)
        acc[m][ct] = __builtin_amdgcn_mfma_f32_16x16x32_bf16(af.v, bfr[ct].v, acc[m][ct], 0, 0, 0);
    }
  }
  #pragma unroll
  for (int m = 0; m < 4; ++m)
    #pragma unroll
    for (int ct = 0; ct < 4; ++ct)
      #pragma unroll
      for (int r = 0; r < 4; ++r)
        weff_bf[((size_t)b * 256 + w * 64 + m * 16 + l4 * 4 + r) * 512 + h * 64 + ct * 16 + l15]
            = f2bfu(acc[m][ct][r]);
}

// ---------------------------------------------------------------------------
// k2: q-proj MFMA + softmax(d) + y = weff @ P MFMA + bias + stats + store
// grid (256 ntiles, 4 b), 256 thr. Wave w = head (4hp+w) for q; o-rows 64w for y.
// ---------------------------------------------------------------------------
__global__ __launch_bounds__(256, 2) void k2_qy(float* outp,
                                                const ushort* __restrict__ wq_bf,
                                                const ushort* __restrict__ weff_bf,
                                                const float* __restrict__ bo,
                                                float* ws) {
  const int t = threadIdx.x, lane = t & 63, w = t >> 6;
  const int l15 = lane & 15, l4 = lane >> 4;
  const int n0 = blockIdx.x * 64, b = blockIdx.y;
  const ushort* xT = (const ushort*)(outp + ((size_t)(b * 512 + 256)) * NN);
  __shared__ __align__(16) ushort xt[64 * 256];
  __shared__ __align__(16) ushort PT[64 * 256];   // P^T for 4 heads (one hp half)
  __shared__ float rsum[4][2], rsq[4][2];
  {
    const int n = t >> 2;
    const ushort* srcp = xT + (size_t)(n0 + n) * 256 + (t & 3) * 64;
    #pragma unroll
    for (int i = 0; i < 8; ++i) {
      const int slot = ((t & 3) * 8 + i) ^ (n & 31);
      *(i32x4*)((char*)xt + n * 512 + slot * 16) = *(const i32x4*)(srcp + i * 8);
    }
  }
  __syncthreads();
  f32x4 yacc[4][4];
  #pragma unroll
  for (int m = 0; m < 4; ++m)
    #pragma unroll
    for (int ct = 0; ct < 4; ++ct) yacc[m][ct] = f32x4{0.f, 0.f, 0.f, 0.f};

  for (int hp = 0; hp < 2; ++hp) {
    const int h = hp * 4 + w;
    f32x4 qacc[4][4];
    #pragma unroll
    for (int mt = 0; mt < 4; ++mt)
      #pragma unroll
      for (int ct = 0; ct < 4; ++ct) qacc[mt][ct] = f32x4{0.f, 0.f, 0.f, 0.f};
    #pragma unroll 2
    for (int ks = 0; ks < 8; ++ks) {
      B16 bfr[4];
      #pragma unroll
      for (int ct = 0; ct < 4; ++ct) {
        const int n = ct * 16 + l15;
        const int slot = (ks * 4 + l4) ^ (n & 31);
        bfr[ct].i = *(const i32x4*)((const char*)xt + n * 512 + slot * 16);
      }
      #pragma unroll
      for (int mt = 0; mt < 4; ++mt) {
        B16 af;
        af.i = *(const i32x4*)(wq_bf + (size_t)(h * 64 + mt * 16 + l15) * 256 + ks * 32 + l4 * 8);
        #pragma unroll
        for (int ct = 0; ct < 4; ++ct)
          qacc[mt][ct] = __builtin_amdgcn_mfma_f32_16x16x32_bf16(af.v, bfr[ct].v, qacc[mt][ct], 0, 0, 0);
      }
    }
    // softmax over d (rows) per column; column d-values live in this lane's 16
    // regs + lanes l^16, l^32, l^48
    #pragma unroll
    for (int ct = 0; ct < 4; ++ct) {
      float sv[4][4]; float mx = -1e30f;
      #pragma unroll
      for (int mt = 0; mt < 4; ++mt)
        #pragma unroll
        for (int r = 0; r < 4; ++r) {
          sv[mt][r] = qacc[mt][ct][r] * QSCALE;
          mx = fmaxf(mx, sv[mt][r]);
        }
      mx = fmaxf(mx, __shfl_xor(mx, 16)); mx = fmaxf(mx, __shfl_xor(mx, 32));
      float ssum = 0.f;
      #pragma unroll
      for (int mt = 0; mt < 4; ++mt)
        #pragma unroll
        for (int r = 0; r < 4; ++r) { sv[mt][r] = __expf(sv[mt][r] - mx); ssum += sv[mt][r]; }
      ssum += __shfl_xor(ssum, 16); ssum += __shfl_xor(ssum, 32);
      const float inv = 1.f / ssum;
      const int n = ct * 16 + l15;
      #pragma unroll
      for (int mt = 0; mt < 4; ++mt)
        #pragma unroll
        for (int rp = 0; rp < 2; ++rp) {
          const uint pk = packbf2(sv[mt][2 * rp] * inv, sv[mt][2 * rp + 1] * inv);
          const int hd = w * 64 + mt * 16 + l4 * 4 + 2 * rp;
          *(uint*)((char*)PT + ((n * 512 + hd * 2) ^ ((n & 31) << 4))) = pk;
        }
    }
    __syncthreads();
    // y += weff[:, hp*256 + k] @ P[k][n]
    #pragma unroll 2
    for (int ks = 0; ks < 8; ++ks) {
      B16 bfr[4];
      #pragma unroll
      for (int ct = 0; ct < 4; ++ct) {
        const int n = ct * 16 + l15;
        const int slot = (ks * 4 + l4) ^ (n & 31);
        bfr[ct].i = *(const i32x4*)((const char*)PT + n * 512 + slot * 16);
      }
      #pragma unroll
      for (int m = 0; m < 4; ++m) {
        B16 af;
        af.i = *(const i32x4*)(weff_bf + ((size_t)b * 256 + w * 64 + m * 16 + l15) * 512
                               + hp * 256 + ks * 32 + l4 * 8);
        #pragma unroll
        for (int ct = 0; ct < 4; ++ct)
          yacc[m][ct] = __builtin_amdgcn_mfma_f32_16x16x32_bf16(af.v, bfr[ct].v, yacc[m][ct], 0, 0, 0);
      }
    }
    __syncthreads();   // before next hp overwrites PT
  }
  // epilogue: bias, group stats (groups 0-7), store
  float sg[2] = {0.f, 0.f}, qg[2] = {0.f, 0.f};
  #pragma unroll
  for (int m = 0; m < 4; ++m) {
    const int o = w * 64 + m * 16 + l4 * 4;
    const f32x4 bv = *(const f32x4*)(bo + o);
    const int gi = m >> 1;
    #pragma unroll
    for (int ct = 0; ct < 4; ++ct)
      #pragma unroll
      for (int r = 0; r < 4; ++r) {
        const float val = yacc[m][ct][r] + bv[r];
        yacc[m][ct][r] = val;
        sg[gi] += val; qg[gi] += val * val;
      }
  }
  #pragma unroll
  for (int msk = 1; msk <= 32; msk <<= 1) {
    sg[0] += __shfl_xor(sg[0], msk); sg[1] += __shfl_xor(sg[1], msk);
    qg[0] += __shfl_xor(qg[0], msk); qg[1] += __shfl_xor(qg[1], msk);
  }
  if (lane == 0) { rsum[w][0] = sg[0]; rsum[w][1] = sg[1]; rsq[w][0] = qg[0]; rsq[w][1] = qg[1]; }
  __syncthreads();
  if (t < 8) {
    atomicAdd(&ws[GSUM_OFF + b * 16 + t], rsum[t >> 1][t & 1]);
    atomicAdd(&ws[GSQ_OFF + b * 16 + t], rsq[t >> 1][t & 1]);
  }
  #pragma unroll
  for (int m = 0; m < 4; ++m)
    #pragma unroll
    for (int ct = 0; ct < 4; ++ct)
      #pragma unroll
      for (int r = 0; r < 4; ++r)
        outp[((size_t)(b * 512) + w * 64 + m * 16 + l4 * 4 + r) * NN + n0 + ct * 16 + l15]
            = yacc[m][ct][r];
}

// ---------------------------------------------------------------------------
// k3: GroupNorm finalize (unchanged from round 1 — it works)
// ---------------------------------------------------------------------------
__global__ __launch_bounds__(256) void k3_groupnorm(
    const float* __restrict__ x, const float* __restrict__ gamma,
    const float* __restrict__ beta, const float* __restrict__ ws,
    float* out) {
  const int t = threadIdx.x;
  const int b = blockIdx.z, ch = blockIdx.y;
  const int n0 = blockIdx.x * 1024 + t * 4;
  const int g = ch >> 5;
  const float s = ws[GSUM_OFF + b * 16 + g];
  const float s2 = ws[GSQ_OFF + b * 16 + g];
  const float mean = s / GRPN;
  const float var = s2 / GRPN - mean * mean;
  const float inv = rsqrtf(var + EPSV);
  const float ga = gamma[ch] * inv;
  const float be = beta[ch] - mean * ga;
  float* op = out + ((size_t)(b * 512) + ch) * NN + n0;
  float4 v;
  if (ch < 256) v = *(const float4*)op;
  else v = *(const float4*)(x + ((size_t)(b * 256) + (ch - 256)) * NN + n0);
  v.x = v.x * ga + be;
  v.y = v.y * ga + be;
  v.z = v.z * ga + be;
  v.w = v.w * ga + be;
  *(float4*)op = v;
}

extern "C" void kernel_launch(void* const* d_in, const int* in_sizes, int n_in,
                              void* d_out, int out_size, void* d_ws, size_t ws_size,
                              hipStream_t stream) {
  const float* x     = (const float*)d_in[0];
  const float* wq    = (const float*)d_in[1];
  const float* wkv   = (const float*)d_in[2];
  const float* wo    = (const float*)d_in[3];
  const float* bo    = (const float*)d_in[4];
  const float* gamma = (const float*)d_in[5];
  const float* beta  = (const float*)d_in[6];
  float* out = (float*)d_out;
  float* ws = (float*)d_ws;

  // scratch carved from d_out's ch256-511 region (k3 overwrites it last)
  float* spare0 = out + (size_t)256 * NN;          // batch-0 spare
  ushort* wq_bf   = (ushort*)(spare0 + 2097152);   // after xT[0] (2.1M floats)
  ushort* wkv_bf  = wq_bf + 131072;
  ushort* wo_bf   = wkv_bf + 262144;
  ushort* weff_bf = wo_bf + 131072;

  hipMemsetAsync(ws, 0, WS_ZERO_FLOATS * sizeof(float), stream);
  k_cvt<<<128, 256, 0, stream>>>(wq,  wq_bf,  131072);
  k_cvt<<<256, 256, 0, stream>>>(wkv, wkv_bf, 262144);
  k_cvt<<<128, 256, 0, stream>>>(wo,  wo_bf,  131072);
  k0_xprep<<<dim3(256, 8, 4), 256, 0, stream>>>(x, out, ws);
  k1_kvctx<<<dim3(32, 8, 4), 256, 0, stream>>>(out, wkv_bf, ws);
  k1b_weff<<<dim3(8, 4), 256, 0, stream>>>(ws, wo_bf, weff_bf);
  k2_qy<<<dim3(256, 4), 256, 0, stream>>>(out, wq_bf, weff_bf, bo, ws);
  k3_groupnorm<<<dim3(16, 512, 4), 256, 0, stream>>>(x, gamma, beta, ws, out);
}

// Round 3
// 327.255 us; speedup vs baseline: 6.3953x; 1.0522x over previous
//
#include <hip/hip_runtime.h>

typedef int    i32x4 __attribute__((ext_vector_type(4)));
typedef float  f32x4 __attribute__((ext_vector_type(4)));
typedef __bf16 bf16x8 __attribute__((ext_vector_type(8)));
union B16 { i32x4 i; bf16x8 v; };

#define NN 16384
#define QSCALE 0.35355339059327373f
#define EPSV 1e-5f
#define GRPN 524288.0f

// ws: only GroupNorm stat accumulators (atomics) remain here.
#define GSUM_OFF 0    // [4][16]
#define GSQ_OFF  64   // [4][16]
#define WS_ZERO_FLOATS 128

// Scratch map inside d_out (overwritten last by k3):
//  batch-0 spare [256ch*NN floats]: xT[0] (2097152 f) | weights (524288 f) | ksump (32768 f)
//  batch-1 spare:                   xT[1] (2097152 f) | ctx partials (2097152 f)
//  batch-2/3 spare:                 xT[2], xT[3]

__device__ __forceinline__ ushort f2bfu(float f) {
  union { __bf16 h; ushort u; } c; c.h = (__bf16)f; return c.u;
}
__device__ __forceinline__ uint packbf2(float lo, float hi) {
  return (uint)f2bfu(lo) | ((uint)f2bfu(hi) << 16);
}
__device__ __forceinline__ void gload_lds16(const void* g, void* l) {
  __builtin_amdgcn_global_load_lds(
      (const __attribute__((address_space(1))) void*)g,
      (__attribute__((address_space(3))) void*)l, 16, 0, 0);
}

// ---------------------------------------------------------------------------
// k_cvt: fp32 -> bf16 weight conversion
// ---------------------------------------------------------------------------
__global__ __launch_bounds__(256) void k_cvt(const float* __restrict__ s,
                                             ushort* __restrict__ d, int n) {
  int i = (blockIdx.x * 256 + threadIdx.x) * 4;
  if (i >= n) return;
  float4 v = *(const float4*)(s + i);
  uint2 p; p.x = packbf2(v.x, v.y); p.y = packbf2(v.z, v.w);
  *(uint2*)(d + i) = p;
}

// ---------------------------------------------------------------------------
// k0: x[b][c][n] f32 -> xT[b][n][c] bf16 (transpose via LDS) + group stats 8-15
// ---------------------------------------------------------------------------
__global__ __launch_bounds__(256) void k0_xprep(const float* __restrict__ x,
                                                float* __restrict__ outp,
                                                float* ws) {
  const int t = threadIdx.x;
  const int n0 = blockIdx.x * 64, cg = blockIdx.y, b = blockIdx.z;
  __shared__ __align__(16) uint tile[64 * 17];
  const int c = t >> 3;           // local channel 0..31
  const int nb = (t & 7) * 8;     // n offset 0..56
  const float* src = x + ((size_t)(b * 256 + cg * 32 + c)) * NN + n0 + nb;
  float v[8];
  { float4 a0 = *(const float4*)src; float4 a1 = *(const float4*)(src + 4);
    v[0]=a0.x; v[1]=a0.y; v[2]=a0.z; v[3]=a0.w; v[4]=a1.x; v[5]=a1.y; v[6]=a1.z; v[7]=a1.w; }
  float s = 0.f, s2 = 0.f;
  #pragma unroll
  for (int j = 0; j < 8; ++j) { s += v[j]; s2 += v[j] * v[j]; }
  float th[8];
  #pragma unroll
  for (int j = 0; j < 8; ++j) th[j] = __shfl_xor(v[j], 8);
  const bool even = ((t >> 3) & 1) == 0;
  const int cp = t >> 4;
  #pragma unroll
  for (int jj = 0; jj < 4; ++jj) {
    const int j = even ? jj : (4 + jj);
    const float lo = even ? v[j] : th[j];
    const float hi = even ? th[j] : v[j];
    tile[(nb + j) * 17 + cp] = packbf2(lo, hi);
  }
  __syncthreads();
  {
    const int n = t >> 2, co = (t & 3) * 4;
    uint o0 = tile[n*17+co], o1 = tile[n*17+co+1], o2 = tile[n*17+co+2], o3 = tile[n*17+co+3];
    ushort* xT = (ushort*)(outp + ((size_t)(b * 512 + 256)) * NN);
    ushort* dst = xT + (size_t)(n0 + n) * 256 + cg * 32 + (t & 3) * 8;
    i32x4 pk; pk[0] = (int)o0; pk[1] = (int)o1; pk[2] = (int)o2; pk[3] = (int)o3;
    *(i32x4*)dst = pk;
  }
  #pragma unroll
  for (int m = 1; m <= 32; m <<= 1) { s += __shfl_xor(s, m); s2 += __shfl_xor(s2, m); }
  __shared__ float rs[4], rq[4];
  const int w = t >> 6;
  if ((t & 63) == 0) { rs[w] = s; rq[w] = s2; }
  __syncthreads();
  if (t == 0) {
    atomicAdd(&ws[GSUM_OFF + b * 16 + 8 + cg], rs[0] + rs[1] + rs[2] + rs[3]);
    atomicAdd(&ws[GSQ_OFF  + b * 16 + 8 + cg], rq[0] + rq[1] + rq[2] + rq[3]);
  }
}

// ---------------------------------------------------------------------------
// k1: 2-phase async MFMA kv-proj + exp(K) + ctx partials.
// grid (16 chunks, 8 h, 4 b), 256 thr (4 waves), 80 KB LDS -> 2 blocks/CU.
// Per subtile (64 n): stage(next) || proj MFMA -> kv bf16 LDS -> ctx MFMA.
// ---------------------------------------------------------------------------
__global__ __launch_bounds__(256, 2) void k1_kvctx(const float* outp,
                                                   const ushort* __restrict__ wkv_bf,
                                                   float* __restrict__ ctxp,
                                                   float* __restrict__ ksump) {
  const int t = threadIdx.x, lane = t & 63, w = t >> 6;
  const int l15 = lane & 15, l4 = lane >> 4;
  const int chunk = blockIdx.x, h = blockIdx.y, b = blockIdx.z;
  const ushort* xT = (const ushort*)(outp + ((size_t)(b * 512 + 256)) * NN);
  __shared__ __align__(16) ushort xt[2][16384];  // 2 x 32 KB, content pre-swizzled
  __shared__ __align__(16) ushort kvb[8192];     // 16 KB: K rows 0-63, V rows 64-127

  // weight A-fragments resident in VGPRs (64 VGPR)
  const int rbase = (w < 2) ? (h * 64 + 32 * w) : (512 + h * 64 + 32 * (w - 2));
  B16 afr[2][8];
  #pragma unroll
  for (int m = 0; m < 2; ++m) {
    const ushort* wr = wkv_bf + (size_t)(rbase + 16 * m + l15) * 256 + l4 * 8;
    #pragma unroll
    for (int ks = 0; ks < 8; ++ks) afr[m][ks].i = *(const i32x4*)(wr + ks * 32);
  }

  const int nbase = chunk * 1024;
  f32x4 ctxc[4];
  #pragma unroll
  for (int ct = 0; ct < 4; ++ct) ctxc[ct] = f32x4{0.f, 0.f, 0.f, 0.f};
  float ksp[2][4] = {};

  // stage subtile st into buf: 8 x global_load_lds_dwordx4 per wave.
  // LDS linear; global source pre-swizzled: lds slot s of row r holds global
  // c-slot s ^ (r & 31)  (16B slots, 32 per 512B row).
  auto STAGE = [&](ushort* bufp, int st) {
    #pragma unroll
    for (int jj = 0; jj < 8; ++jj) {
      const int j = w * 8 + jj;              // 1KB chunk = 2 rows
      const int rl = 2 * j + (lane >> 5);
      const int slot = (lane & 31) ^ (rl & 31);
      const ushort* gp = xT + (size_t)(nbase + st * 64 + rl) * 256 + slot * 8;
      gload_lds16(gp, bufp + (size_t)j * 512);
    }
  };

  STAGE(xt[0], 0);
  asm volatile("s_waitcnt vmcnt(0)" ::: "memory");
  __builtin_amdgcn_s_barrier();

  for (int st = 0; st < 16; ++st) {
    const int cur = st & 1;
    if (st < 15) STAGE(xt[cur ^ 1], st + 1);
    const ushort* xb = xt[cur];

    // proj: wave w -> rows 32w..32w+31 (K for w<2, V for w>=2), 64 n cols
    f32x4 acc[2][4];
    #pragma unroll
    for (int m = 0; m < 2; ++m)
      #pragma unroll
      for (int ct = 0; ct < 4; ++ct) acc[m][ct] = f32x4{0.f, 0.f, 0.f, 0.f};
    #pragma unroll 2
    for (int ks = 0; ks < 8; ++ks) {
      B16 bfr[4];
      #pragma unroll
      for (int ct = 0; ct < 4; ++ct) {
        const int n = ct * 16 + l15;
        const int slot = (ks * 4 + l4) ^ (n & 31);
        bfr[ct].i = *(const i32x4*)((const char*)xb + n * 512 + slot * 16);
      }
      #pragma unroll
      for (int m = 0; m < 2; ++m)
        #pragma unroll
        for (int ct = 0; ct < 4; ++ct)
          acc[m][ct] = __builtin_amdgcn_mfma_f32_16x16x32_bf16(afr[m][ks].v, bfr[ct].v, acc[m][ct], 0, 0, 0);
    }

    // write K (exp'd) / V to kvb as bf16, slot-XOR swizzled (slot ^= row&7)
    if (w < 2) {
      #pragma unroll
      for (int m = 0; m < 2; ++m) {
        const int dbase = 32 * w + 16 * m + l4 * 4;
        #pragma unroll
        for (int ct = 0; ct < 4; ++ct) {
          const int n = ct * 16 + l15;
          #pragma unroll
          for (int r = 0; r < 4; ++r) {
            const int d = dbase + r;
            const float e = __expf(acc[m][ct][r] * QSCALE);
            ksp[m][r] += e;
            *(ushort*)((char*)kvb + d * 128 + (((n >> 3) ^ (d & 7)) << 4) + (n & 7) * 2) = f2bfu(e);
          }
        }
      }
    } else {
      #pragma unroll
      for (int m = 0; m < 2; ++m) {
        const int ebase = 64 + 32 * (w - 2) + 16 * m + l4 * 4;
        #pragma unroll
        for (int ct = 0; ct < 4; ++ct) {
          const int n = ct * 16 + l15;
          #pragma unroll
          for (int r = 0; r < 4; ++r) {
            const int row = ebase + r;
            *(ushort*)((char*)kvb + row * 128 + (((n >> 3) ^ (row & 7)) << 4) + (n & 7) * 2)
                = f2bfu(acc[m][ct][r]);
          }
        }
      }
    }
    // kv visible to all waves; staging loads stay in flight (no vmcnt drain!)
    asm volatile("s_waitcnt lgkmcnt(0)" ::: "memory");
    __builtin_amdgcn_s_barrier();

    // ctx: wave w -> d rows 16w..16w+15; ctx[d][e] += Kexp[d][n] V[e][n]
    #pragma unroll
    for (int ks = 0; ks < 2; ++ks) {
      const int dA = 16 * w + l15;
      B16 a;
      a.i = *(const i32x4*)((const char*)kvb + dA * 128 + (((ks * 4 + l4) ^ (dA & 7)) << 4));
      #pragma unroll
      for (int ct = 0; ct < 4; ++ct) {
        const int rowB = 64 + ct * 16 + l15;
        B16 bb;
        bb.i = *(const i32x4*)((const char*)kvb + rowB * 128 + (((ks * 4 + l4) ^ (rowB & 7)) << 4));
        ctxc[ct] = __builtin_amdgcn_mfma_f32_16x16x32_bf16(a.v, bb.v, ctxc[ct], 0, 0, 0);
      }
    }
    if (st < 15) {
      // next subtile's buffer staged + all LDS reads retired before reuse
      asm volatile("s_waitcnt vmcnt(0) lgkmcnt(0)" ::: "memory");
      __builtin_amdgcn_s_barrier();
    }
  }

  // epilogue: per-block partials (no atomics)
  if (w < 2) {
    #pragma unroll
    for (int m = 0; m < 2; ++m)
      #pragma unroll
      for (int r = 0; r < 4; ++r) {
        float s = ksp[m][r];
        s += __shfl_xor(s, 1); s += __shfl_xor(s, 2);
        s += __shfl_xor(s, 4); s += __shfl_xor(s, 8);
        if (l15 == 0)
          ksump[chunk * 2048 + (b * 8 + h) * 64 + 32 * w + 16 * m + l4 * 4 + r] = s;
      }
  }
  float* cp = ctxp + (size_t)chunk * 131072 + (size_t)(b * 8 + h) * 4096;
  #pragma unroll
  for (int ct = 0; ct < 4; ++ct)
    #pragma unroll
    for (int r = 0; r < 4; ++r)
      cp[(16 * w + l4 * 4 + r) * 64 + ct * 16 + l15] = ctxc[ct][r];
}

// ---------------------------------------------------------------------------
// k1b: reduce ctx/ksum partials, then weff = wo @ (ctx/ksum). grid (8,4).
// ---------------------------------------------------------------------------
__global__ __launch_bounds__(256) void k1b_weff(const float* __restrict__ ctxp,
                                                const float* __restrict__ ksump,
                                                const ushort* __restrict__ wo_bf,
                                                ushort* __restrict__ weff_bf) {
  const int t = threadIdx.x, lane = t & 63, w = t >> 6;
  const int l15 = lane & 15, l4 = lane >> 4;
  const int h = blockIdx.x, b = blockIdx.y;
  __shared__ float ksinv[64];
  __shared__ __align__(16) float ctxs[64 * 68];
  if (t < 64) {
    float s = 0.f;
    #pragma unroll
    for (int c = 0; c < 16; ++c) s += ksump[c * 2048 + (b * 8 + h) * 64 + t];
    ksinv[t] = 1.f / s;
  }
  for (int i = t; i < 4096; i += 256) {
    float s = 0.f;
    #pragma unroll
    for (int c = 0; c < 16; ++c) s += ctxp[(size_t)c * 131072 + (b * 8 + h) * 4096 + i];
    ctxs[(i >> 6) * 68 + (i & 63)] = s;
  }
  __syncthreads();
  f32x4 acc[4][4];
  #pragma unroll
  for (int m = 0; m < 4; ++m)
    #pragma unroll
    for (int ct = 0; ct < 4; ++ct) acc[m][ct] = f32x4{0.f, 0.f, 0.f, 0.f};
  #pragma unroll
  for (int ks = 0; ks < 2; ++ks) {
    B16 bfr[4];
    #pragma unroll
    for (int ct = 0; ct < 4; ++ct) {
      const int d = ct * 16 + l15;
      const float inv = ksinv[d];
      const float* bp = &ctxs[d * 68 + ks * 32 + l4 * 8];
      #pragma unroll
      for (int j = 0; j < 4; ++j) {
        bfr[ct].v[j] = (__bf16)(bp[j] * inv);
        bfr[ct].v[4 + j] = (__bf16)(bp[4 + j] * inv);
      }
    }
    #pragma unroll
    for (int m = 0; m < 4; ++m) {
      B16 af;
      af.i = *(const i32x4*)(wo_bf + (size_t)(w * 64 + m * 16 + l15) * 512 + h * 64 + ks * 32 + l4 * 8);
      #pragma unroll
      for (int ct = 0; ct < 4; ++ct)
        acc[m][ct] = __builtin_amdgcn_mfma_f32_16x16x32_bf16(af.v, bfr[ct].v, acc[m][ct], 0, 0, 0);
    }
  }
  #pragma unroll
  for (int m = 0; m < 4; ++m)
    #pragma unroll
    for (int ct = 0; ct < 4; ++ct)
      #pragma unroll
      for (int r = 0; r < 4; ++r)
        weff_bf[((size_t)b * 256 + w * 64 + m * 16 + l4 * 4 + r) * 512 + h * 64 + ct * 16 + l15]
            = f2bfu(acc[m][ct][r]);
}

// ---------------------------------------------------------------------------
// k2: q-proj MFMA + softmax(d) + y = weff @ P MFMA + bias + stats + store
// (unchanged from round 2)
// ---------------------------------------------------------------------------
__global__ __launch_bounds__(256, 2) void k2_qy(float* outp,
                                                const ushort* __restrict__ wq_bf,
                                                const ushort* __restrict__ weff_bf,
                                                const float* __restrict__ bo,
                                                float* ws) {
  const int t = threadIdx.x, lane = t & 63, w = t >> 6;
  const int l15 = lane & 15, l4 = lane >> 4;
  const int n0 = blockIdx.x * 64, b = blockIdx.y;
  const ushort* xT = (const ushort*)(outp + ((size_t)(b * 512 + 256)) * NN);
  __shared__ __align__(16) ushort xt[64 * 256];
  __shared__ __align__(16) ushort PT[64 * 256];
  __shared__ float rsum[4][2], rsq[4][2];
  {
    const int n = t >> 2;
    const ushort* srcp = xT + (size_t)(n0 + n) * 256 + (t & 3) * 64;
    #pragma unroll
    for (int i = 0; i < 8; ++i) {
      const int slot = ((t & 3) * 8 + i) ^ (n & 31);
      *(i32x4*)((char*)xt + n * 512 + slot * 16) = *(const i32x4*)(srcp + i * 8);
    }
  }
  __syncthreads();
  f32x4 yacc[4][4];
  #pragma unroll
  for (int m = 0; m < 4; ++m)
    #pragma unroll
    for (int ct = 0; ct < 4; ++ct) yacc[m][ct] = f32x4{0.f, 0.f, 0.f, 0.f};

  for (int hp = 0; hp < 2; ++hp) {
    const int h = hp * 4 + w;
    f32x4 qacc[4][4];
    #pragma unroll
    for (int mt = 0; mt < 4; ++mt)
      #pragma unroll
      for (int ct = 0; ct < 4; ++ct) qacc[mt][ct] = f32x4{0.f, 0.f, 0.f, 0.f};
    #pragma unroll 2
    for (int ks = 0; ks < 8; ++ks) {
      B16 bfr[4];
      #pragma unroll
      for (int ct = 0; ct < 4; ++ct) {
        const int n = ct * 16 + l15;
        const int slot = (ks * 4 + l4) ^ (n & 31);
        bfr[ct].i = *(const i32x4*)((const char*)xt + n * 512 + slot * 16);
      }
      #pragma unroll
      for (int mt = 0; mt < 4; ++mt) {
        B16 af;
        af.i = *(const i32x4*)(wq_bf + (size_t)(h * 64 + mt * 16 + l15) * 256 + ks * 32 + l4 * 8);
        #pragma unroll
        for (int ct = 0; ct < 4; ++ct)
          qacc[mt][ct] = __builtin_amdgcn_mfma_f32_16x16x32_bf16(af.v, bfr[ct].v, qacc[mt][ct], 0, 0, 0);
      }
    }
    #pragma unroll
    for (int ct = 0; ct < 4; ++ct) {
      float sv[4][4]; float mx = -1e30f;
      #pragma unroll
      for (int mt = 0; mt < 4; ++mt)
        #pragma unroll
        for (int r = 0; r < 4; ++r) {
          sv[mt][r] = qacc[mt][ct][r] * QSCALE;
          mx = fmaxf(mx, sv[mt][r]);
        }
      mx = fmaxf(mx, __shfl_xor(mx, 16)); mx = fmaxf(mx, __shfl_xor(mx, 32));
      float ssum = 0.f;
      #pragma unroll
      for (int mt = 0; mt < 4; ++mt)
        #pragma unroll
        for (int r = 0; r < 4; ++r) { sv[mt][r] = __expf(sv[mt][r] - mx); ssum += sv[mt][r]; }
      ssum += __shfl_xor(ssum, 16); ssum += __shfl_xor(ssum, 32);
      const float inv = 1.f / ssum;
      const int n = ct * 16 + l15;
      #pragma unroll
      for (int mt = 0; mt < 4; ++mt)
        #pragma unroll
        for (int rp = 0; rp < 2; ++rp) {
          const uint pk = packbf2(sv[mt][2 * rp] * inv, sv[mt][2 * rp + 1] * inv);
          const int hd = w * 64 + mt * 16 + l4 * 4 + 2 * rp;
          *(uint*)((char*)PT + ((n * 512 + hd * 2) ^ ((n & 31) << 4))) = pk;
        }
    }
    __syncthreads();
    #pragma unroll 2
    for (int ks = 0; ks < 8; ++ks) {
      B16 bfr[4];
      #pragma unroll
      for (int ct = 0; ct < 4; ++ct) {
        const int n = ct * 16 + l15;
        const int slot = (ks * 4 + l4) ^ (n & 31);
        bfr[ct].i = *(const i32x4*)((const char*)PT + n * 512 + slot * 16);
      }
      #pragma unroll
      for (int m = 0; m < 4; ++m) {
        B16 af;
        af.i = *(const i32x4*)(weff_bf + ((size_t)b * 256 + w * 64 + m * 16 + l15) * 512
                               + hp * 256 + ks * 32 + l4 * 8);
        #pragma unroll
        for (int ct = 0; ct < 4; ++ct)
          yacc[m][ct] = __builtin_amdgcn_mfma_f32_16x16x32_bf16(af.v, bfr[ct].v, yacc[m][ct], 0, 0, 0);
      }
    }
    __syncthreads();
  }
  float sg[2] = {0.f, 0.f}, qg[2] = {0.f, 0.f};
  #pragma unroll
  for (int m = 0; m < 4; ++m) {
    const int o = w * 64 + m * 16 + l4 * 4;
    const f32x4 bv = *(const f32x4*)(bo + o);
    const int gi = m >> 1;
    #pragma unroll
    for (int ct = 0; ct < 4; ++ct)
      #pragma unroll
      for (int r = 0; r < 4; ++r) {
        const float val = yacc[m][ct][r] + bv[r];
        yacc[m][ct][r] = val;
        sg[gi] += val; qg[gi] += val * val;
      }
  }
  #pragma unroll
  for (int msk = 1; msk <= 32; msk <<= 1) {
    sg[0] += __shfl_xor(sg[0], msk); sg[1] += __shfl_xor(sg[1], msk);
    qg[0] += __shfl_xor(qg[0], msk); qg[1] += __shfl_xor(qg[1], msk);
  }
  if (lane == 0) { rsum[w][0] = sg[0]; rsum[w][1] = sg[1]; rsq[w][0] = qg[0]; rsq[w][1] = qg[1]; }
  __syncthreads();
  if (t < 8) {
    atomicAdd(&ws[GSUM_OFF + b * 16 + t], rsum[t >> 1][t & 1]);
    atomicAdd(&ws[GSQ_OFF + b * 16 + t], rsq[t >> 1][t & 1]);
  }
  #pragma unroll
  for (int m = 0; m < 4; ++m)
    #pragma unroll
    for (int ct = 0; ct < 4; ++ct)
      #pragma unroll
      for (int r = 0; r < 4; ++r)
        outp[((size_t)(b * 512) + w * 64 + m * 16 + l4 * 4 + r) * NN + n0 + ct * 16 + l15]
            = yacc[m][ct][r];
}

// ---------------------------------------------------------------------------
// k3: GroupNorm finalize (unchanged)
// ---------------------------------------------------------------------------
__global__ __launch_bounds__(256) void k3_groupnorm(
    const float* __restrict__ x, const float* __restrict__ gamma,
    const float* __restrict__ beta, const float* __restrict__ ws,
    float* out) {
  const int t = threadIdx.x;
  const int b = blockIdx.z, ch = blockIdx.y;
  const int n0 = blockIdx.x * 1024 + t * 4;
  const int g = ch >> 5;
  const float s = ws[GSUM_OFF + b * 16 + g];
  const float s2 = ws[GSQ_OFF + b * 16 + g];
  const float mean = s / GRPN;
  const float var = s2 / GRPN - mean * mean;
  const float inv = rsqrtf(var + EPSV);
  const float ga = gamma[ch] * inv;
  const float be = beta[ch] - mean * ga;
  float* op = out + ((size_t)(b * 512) + ch) * NN + n0;
  float4 v;
  if (ch < 256) v = *(const float4*)op;
  else v = *(const float4*)(x + ((size_t)(b * 256) + (ch - 256)) * NN + n0);
  v.x = v.x * ga + be;
  v.y = v.y * ga + be;
  v.z = v.z * ga + be;
  v.w = v.w * ga + be;
  *(float4*)op = v;
}

extern "C" void kernel_launch(void* const* d_in, const int* in_sizes, int n_in,
                              void* d_out, int out_size, void* d_ws, size_t ws_size,
                              hipStream_t stream) {
  const float* x     = (const float*)d_in[0];
  const float* wq    = (const float*)d_in[1];
  const float* wkv   = (const float*)d_in[2];
  const float* wo    = (const float*)d_in[3];
  const float* bo    = (const float*)d_in[4];
  const float* gamma = (const float*)d_in[5];
  const float* beta  = (const float*)d_in[6];
  float* out = (float*)d_out;
  float* ws = (float*)d_ws;

  // scratch carved from d_out ch256-511 regions (k3 overwrites them last)
  float* spare0 = out + (size_t)256 * NN;
  ushort* wq_bf   = (ushort*)(spare0 + 2097152);   // after xT[0]
  ushort* wkv_bf  = wq_bf + 131072;
  ushort* wo_bf   = wkv_bf + 262144;
  ushort* weff_bf = wo_bf + 131072;
  float*  ksump   = (float*)(weff_bf + 524288);    // 32768 floats
  float*  ctxp    = out + (size_t)768 * NN + 2097152;  // batch-1 spare, 2097152 floats

  hipMemsetAsync(ws, 0, WS_ZERO_FLOATS * sizeof(float), stream);
  k_cvt<<<128, 256, 0, stream>>>(wq,  wq_bf,  131072);
  k_cvt<<<256, 256, 0, stream>>>(wkv, wkv_bf, 262144);
  k_cvt<<<128, 256, 0, stream>>>(wo,  wo_bf,  131072);
  k0_xprep<<<dim3(256, 8, 4), 256, 0, stream>>>(x, out, ws);
  k1_kvctx<<<dim3(16, 8, 4), 256, 0, stream>>>(out, wkv_bf, ctxp, ksump);
  k1b_weff<<<dim3(8, 4), 256, 0, stream>>>(ctxp, ksump, wo_bf, weff_bf);
  k2_qy<<<dim3(256, 4), 256, 0, stream>>>(out, wq_bf, weff_bf, bo, ws);
  k3_groupnorm<<<dim3(16, 512, 4), 256, 0, stream>>>(x, gamma, beta, ws, out);
}

// Round 4
// 305.726 us; speedup vs baseline: 6.8457x; 1.0704x over previous
//
#include <hip/hip_runtime.h>

typedef int    i32x4 __attribute__((ext_vector_type(4)));
typedef float  f32x4 __attribute__((ext_vector_type(4)));
typedef __bf16 bf16x8 __attribute__((ext_vector_type(8)));
union B16 { i32x4 i; bf16x8 v; };

#define NN 16384
#define QSCALE 0.35355339059327373f
#define EPSV 1e-5f
#define GRPN 524288.0f

// ws: only GroupNorm stat accumulators (atomics) remain here.
#define GSUM_OFF 0    // [4][16]
#define GSQ_OFF  64   // [4][16]
#define WS_ZERO_FLOATS 128

// Scratch map inside d_out (overwritten last by k3). Per-batch spare region =
// out + (b*512+256)*NN floats, 4194304 floats each; xT[b] bf16 occupies the
// first 2097152 floats. Remaining 2097152 floats per batch:
//  b0: weights (wq/wkv/wo/weff bf16) + ksump
//  b2: ctx partials chunks 0-15   b3: ctx partials chunks 16-31

__device__ __forceinline__ ushort f2bfu(float f) {
  union { __bf16 h; ushort u; } c; c.h = (__bf16)f; return c.u;
}
__device__ __forceinline__ uint packbf2(float lo, float hi) {
  return (uint)f2bfu(lo) | ((uint)f2bfu(hi) << 16);
}
__device__ __forceinline__ void gload_lds16(const void* g, void* l) {
  __builtin_amdgcn_global_load_lds(
      (const __attribute__((address_space(1))) void*)g,
      (__attribute__((address_space(3))) void*)l, 16, 0, 0);
}

// ---------------------------------------------------------------------------
// k_cvt: fp32 -> bf16 weight conversion
// ---------------------------------------------------------------------------
__global__ __launch_bounds__(256) void k_cvt(const float* __restrict__ s,
                                             ushort* __restrict__ d, int n) {
  int i = (blockIdx.x * 256 + threadIdx.x) * 4;
  if (i >= n) return;
  float4 v = *(const float4*)(s + i);
  uint2 p; p.x = packbf2(v.x, v.y); p.y = packbf2(v.z, v.w);
  *(uint2*)(d + i) = p;
}

// ---------------------------------------------------------------------------
// k0: x[b][c][n] f32 -> xT[b][n][c] bf16 (transpose via LDS) + group stats 8-15
// ---------------------------------------------------------------------------
__global__ __launch_bounds__(256) void k0_xprep(const float* __restrict__ x,
                                                float* __restrict__ outp,
                                                float* ws) {
  const int t = threadIdx.x;
  const int n0 = blockIdx.x * 64, cg = blockIdx.y, b = blockIdx.z;
  __shared__ __align__(16) uint tile[64 * 17];
  const int c = t >> 3;           // local channel 0..31
  const int nb = (t & 7) * 8;     // n offset 0..56
  const float* src = x + ((size_t)(b * 256 + cg * 32 + c)) * NN + n0 + nb;
  float v[8];
  { float4 a0 = *(const float4*)src; float4 a1 = *(const float4*)(src + 4);
    v[0]=a0.x; v[1]=a0.y; v[2]=a0.z; v[3]=a0.w; v[4]=a1.x; v[5]=a1.y; v[6]=a1.z; v[7]=a1.w; }
  float s = 0.f, s2 = 0.f;
  #pragma unroll
  for (int j = 0; j < 8; ++j) { s += v[j]; s2 += v[j] * v[j]; }
  float th[8];
  #pragma unroll
  for (int j = 0; j < 8; ++j) th[j] = __shfl_xor(v[j], 8);
  const bool even = ((t >> 3) & 1) == 0;
  const int cp = t >> 4;
  #pragma unroll
  for (int jj = 0; jj < 4; ++jj) {
    const int j = even ? jj : (4 + jj);
    const float lo = even ? v[j] : th[j];
    const float hi = even ? th[j] : v[j];
    tile[(nb + j) * 17 + cp] = packbf2(lo, hi);
  }
  __syncthreads();
  {
    const int n = t >> 2, co = (t & 3) * 4;
    uint o0 = tile[n*17+co], o1 = tile[n*17+co+1], o2 = tile[n*17+co+2], o3 = tile[n*17+co+3];
    ushort* xT = (ushort*)(outp + ((size_t)(b * 512 + 256)) * NN);
    ushort* dst = xT + (size_t)(n0 + n) * 256 + cg * 32 + (t & 3) * 8;
    i32x4 pk; pk[0] = (int)o0; pk[1] = (int)o1; pk[2] = (int)o2; pk[3] = (int)o3;
    *(i32x4*)dst = pk;
  }
  #pragma unroll
  for (int m = 1; m <= 32; m <<= 1) { s += __shfl_xor(s, m); s2 += __shfl_xor(s2, m); }
  __shared__ float rs[4], rq[4];
  const int w = t >> 6;
  if ((t & 63) == 0) { rs[w] = s; rq[w] = s2; }
  __syncthreads();
  if (t == 0) {
    atomicAdd(&ws[GSUM_OFF + b * 16 + 8 + cg], rs[0] + rs[1] + rs[2] + rs[3]);
    atomicAdd(&ws[GSQ_OFF  + b * 16 + 8 + cg], rq[0] + rq[1] + rq[2] + rq[3]);
  }
}

// ---------------------------------------------------------------------------
// k1: 4-heads-per-block MFMA kv-proj + exp(K) + ctx (register-resident).
// grid (32 chunks of 512 n, 2 hquads, 4 b) = 256 blocks, 512 thr (8 waves).
// x-tile read ONCE per head-quad; wkv A-frags for 4 heads resident in VGPRs.
// 2-phase async staging with counted vmcnt (only vmem in the loop).
// ---------------------------------------------------------------------------
__global__ __launch_bounds__(512, 2) void k1_kvctx(const float* outp,
                                                   const ushort* __restrict__ wkv_bf,
                                                   float* __restrict__ ctxpA,
                                                   float* __restrict__ ctxpB,
                                                   float* __restrict__ ksump) {
  const int t = threadIdx.x, lane = t & 63, w = t >> 6;   // 8 waves
  const int l15 = lane & 15, l4 = lane >> 4;
  const int chunk = blockIdx.x, hq = blockIdx.y, b = blockIdx.z;
  const ushort* xT = (const ushort*)(outp + ((size_t)(b * 512 + 256)) * NN);
  __shared__ __align__(16) ushort xt[2][16384];  // 2 x 32 KB, pre-swizzled content
  __shared__ __align__(16) ushort kvb[8192];     // 16 KB: K rows 0-63, V rows 64-127

  const int nbase = chunk * 512;

  // stage one 64-n subtile (32 KB): 4 x global_load_lds_dwordx4 per lane.
  // LDS linear; global source pre-swizzled: LDS slot s of row r holds global
  // 16B-slot s ^ (r & 31).
  auto STAGE = [&](ushort* bufp, int st) {
    #pragma unroll
    for (int j = 0; j < 4; ++j) {
      const int rl = w * 8 + j * 2 + (lane >> 5);
      const int slot = (lane & 31) ^ (rl & 31);
      const ushort* gp = xT + (size_t)(nbase + st * 64 + rl) * 256 + slot * 8;
      gload_lds16(gp, bufp + (w * 8 + j * 2) * 256);
    }
  };

  STAGE(xt[0], 0);

  // preload wkv A-fragments for 4 heads: wave w owns m-tile w
  // (w<4: K rows 16w..16w+15; w>=4: V rows 512+16(w-4)..)
  const int rbase0 = (w < 4) ? (16 * w) : (512 + 16 * (w - 4));
  B16 afr[4][8];
  #pragma unroll
  for (int hi = 0; hi < 4; ++hi) {
    const int h = hq * 4 + hi;
    const ushort* wr = wkv_bf + (size_t)(rbase0 + h * 64 + l15) * 256 + l4 * 8;
    #pragma unroll
    for (int ks = 0; ks < 8; ++ks) afr[hi][ks].i = *(const i32x4*)(wr + ks * 32);
  }

  f32x4 ctxc[4][2];   // [hi][ct-half] — wave w: d-tile w&3, e-half w>>2
  #pragma unroll
  for (int hi = 0; hi < 4; ++hi)
    #pragma unroll
    for (int ct = 0; ct < 2; ++ct) ctxc[hi][ct] = f32x4{0.f, 0.f, 0.f, 0.f};
  float ksp[4][4] = {};   // K-waves: per-hi, per-r row sums

  asm volatile("s_waitcnt vmcnt(0)" ::: "memory");
  __builtin_amdgcn_s_barrier();

  for (int st = 0; st < 8; ++st) {
    const int cur = st & 1;
    if (st < 7) {
      STAGE(xt[cur ^ 1], st + 1);
      asm volatile("s_waitcnt vmcnt(4)" ::: "memory");  // prior stage landed
    } else {
      asm volatile("s_waitcnt vmcnt(0)" ::: "memory");
    }
    __builtin_amdgcn_s_barrier();
    const ushort* xb = xt[cur];

    #pragma unroll
    for (int hi = 0; hi < 4; ++hi) {
      // proj: 16 rows (m-tile w) x 64 n, K=256
      f32x4 acc[4];
      #pragma unroll
      for (int ct = 0; ct < 4; ++ct) acc[ct] = f32x4{0.f, 0.f, 0.f, 0.f};
      #pragma unroll
      for (int ks = 0; ks < 8; ++ks) {
        B16 bfr[4];
        #pragma unroll
        for (int ct = 0; ct < 4; ++ct) {
          const int n = ct * 16 + l15;
          const int slot = (ks * 4 + l4) ^ (n & 31);
          bfr[ct].i = *(const i32x4*)((const char*)xb + n * 512 + slot * 16);
        }
        #pragma unroll
        for (int ct = 0; ct < 4; ++ct)
          acc[ct] = __builtin_amdgcn_mfma_f32_16x16x32_bf16(afr[hi][ks].v, bfr[ct].v, acc[ct], 0, 0, 0);
      }
      // write kv rows (bf16, slot-XOR swz); K waves also exp + ksum
      {
        const int row0 = 16 * w + l4 * 4;     // uniform: K rows 0-63, V rows 64-127
        #pragma unroll
        for (int ct = 0; ct < 4; ++ct) {
          const int n = ct * 16 + l15;
          #pragma unroll
          for (int r = 0; r < 4; ++r) {
            float vv = acc[ct][r];
            if (w < 4) { vv = __expf(vv * QSCALE); ksp[hi][r] += vv; }
            const int row = row0 + r;
            *(ushort*)((char*)kvb + row * 128 + ((((n >> 3) ^ (row & 7))) << 4) + (n & 7) * 2)
                = f2bfu(vv);
          }
        }
      }
      asm volatile("s_waitcnt lgkmcnt(0)" ::: "memory");
      __builtin_amdgcn_s_barrier();
      // ctx: wave w: d-tile dt=w&3 (16 rows), e-half eh=w>>2 (32 cols), K=64
      #pragma unroll
      for (int ks = 0; ks < 2; ++ks) {
        const int ar = 16 * (w & 3) + l15;
        B16 a;
        a.i = *(const i32x4*)((const char*)kvb + ar * 128 + (((ks * 4 + l4) ^ (ar & 7)) << 4));
        #pragma unroll
        for (int ct = 0; ct < 2; ++ct) {
          const int br = 64 + (w >> 2) * 32 + ct * 16 + l15;
          B16 bb;
          bb.i = *(const i32x4*)((const char*)kvb + br * 128 + (((ks * 4 + l4) ^ (br & 7)) << 4));
          ctxc[hi][ct] = __builtin_amdgcn_mfma_f32_16x16x32_bf16(a.v, bb.v, ctxc[hi][ct], 0, 0, 0);
        }
      }
      if (hi < 3) __builtin_amdgcn_s_barrier();  // before next hi's kv writes
    }
  }

  // epilogue: per-block partials (streaming stores, no atomics)
  if (w < 4) {
    #pragma unroll
    for (int hi = 0; hi < 4; ++hi)
      #pragma unroll
      for (int r = 0; r < 4; ++r) {
        float s = ksp[hi][r];
        s += __shfl_xor(s, 1); s += __shfl_xor(s, 2);
        s += __shfl_xor(s, 4); s += __shfl_xor(s, 8);
        if (l15 == 0)
          ksump[chunk * 2048 + (b * 8 + hq * 4 + hi) * 64 + 16 * w + l4 * 4 + r] = s;
      }
  }
  float* base = (chunk < 16 ? ctxpA : ctxpB) + (size_t)(chunk & 15) * 131072;
  #pragma unroll
  for (int hi = 0; hi < 4; ++hi) {
    float* cp = base + (size_t)(b * 8 + hq * 4 + hi) * 4096;
    #pragma unroll
    for (int ct = 0; ct < 2; ++ct)
      #pragma unroll
      for (int r = 0; r < 4; ++r)
        cp[(16 * (w & 3) + l4 * 4 + r) * 64 + (w >> 2) * 32 + ct * 16 + l15] = ctxc[hi][ct][r];
  }
}

// ---------------------------------------------------------------------------
// k1b: reduce ctx/ksum partials (32 chunks), then weff = wo @ (ctx/ksum).
// grid (8 h, 4 b), 256 thr.
// ---------------------------------------------------------------------------
__global__ __launch_bounds__(256) void k1b_weff(const float* __restrict__ ctxpA,
                                                const float* __restrict__ ctxpB,
                                                const float* __restrict__ ksump,
                                                const ushort* __restrict__ wo_bf,
                                                ushort* __restrict__ weff_bf) {
  const int t = threadIdx.x, lane = t & 63, w = t >> 6;
  const int l15 = lane & 15, l4 = lane >> 4;
  const int h = blockIdx.x, b = blockIdx.y;
  __shared__ float ksinv[64];
  __shared__ __align__(16) float ctxs[64 * 68];
  if (t < 64) {
    float s = 0.f;
    #pragma unroll
    for (int c = 0; c < 32; ++c) s += ksump[c * 2048 + (b * 8 + h) * 64 + t];
    ksinv[t] = 1.f / s;
  }
  const int off = (b * 8 + h) * 4096;
  for (int i = t; i < 4096; i += 256) {
    float s = 0.f;
    #pragma unroll
    for (int c = 0; c < 16; ++c) s += ctxpA[(size_t)c * 131072 + off + i];
    #pragma unroll
    for (int c = 0; c < 16; ++c) s += ctxpB[(size_t)c * 131072 + off + i];
    ctxs[(i >> 6) * 68 + (i & 63)] = s;
  }
  __syncthreads();
  f32x4 acc[4][4];
  #pragma unroll
  for (int m = 0; m < 4; ++m)
    #pragma unroll
    for (int ct = 0; ct < 4; ++ct) acc[m][ct] = f32x4{0.f, 0.f, 0.f, 0.f};
  #pragma unroll
  for (int ks = 0; ks < 2; ++ks) {
    B16 bfr[4];
    #pragma unroll
    for (int ct = 0; ct < 4; ++ct) {
      const int d = ct * 16 + l15;
      const float inv = ksinv[d];
      const float* bp = &ctxs[d * 68 + ks * 32 + l4 * 8];
      #pragma unroll
      for (int j = 0; j < 4; ++j) {
        bfr[ct].v[j] = (__bf16)(bp[j] * inv);
        bfr[ct].v[4 + j] = (__bf16)(bp[4 + j] * inv);
      }
    }
    #pragma unroll
    for (int m = 0; m < 4; ++m) {
      B16 af;
      af.i = *(const i32x4*)(wo_bf + (size_t)(w * 64 + m * 16 + l15) * 512 + h * 64 + ks * 32 + l4 * 8);
      #pragma unroll
      for (int ct = 0; ct < 4; ++ct)
        acc[m][ct] = __builtin_amdgcn_mfma_f32_16x16x32_bf16(af.v, bfr[ct].v, acc[m][ct], 0, 0, 0);
    }
  }
  #pragma unroll
  for (int m = 0; m < 4; ++m)
    #pragma unroll
    for (int ct = 0; ct < 4; ++ct)
      #pragma unroll
      for (int r = 0; r < 4; ++r)
        weff_bf[((size_t)b * 256 + w * 64 + m * 16 + l4 * 4 + r) * 512 + h * 64 + ct * 16 + l15]
            = f2bfu(acc[m][ct][r]);
}

// ---------------------------------------------------------------------------
// k2: q-proj MFMA + softmax(d) + y = weff @ P MFMA + bias + stats + store
// (unchanged)
// ---------------------------------------------------------------------------
__global__ __launch_bounds__(256, 2) void k2_qy(float* outp,
                                                const ushort* __restrict__ wq_bf,
                                                const ushort* __restrict__ weff_bf,
                                                const float* __restrict__ bo,
                                                float* ws) {
  const int t = threadIdx.x, lane = t & 63, w = t >> 6;
  const int l15 = lane & 15, l4 = lane >> 4;
  const int n0 = blockIdx.x * 64, b = blockIdx.y;
  const ushort* xT = (const ushort*)(outp + ((size_t)(b * 512 + 256)) * NN);
  __shared__ __align__(16) ushort xt[64 * 256];
  __shared__ __align__(16) ushort PT[64 * 256];
  __shared__ float rsum[4][2], rsq[4][2];
  {
    const int n = t >> 2;
    const ushort* srcp = xT + (size_t)(n0 + n) * 256 + (t & 3) * 64;
    #pragma unroll
    for (int i = 0; i < 8; ++i) {
      const int slot = ((t & 3) * 8 + i) ^ (n & 31);
      *(i32x4*)((char*)xt + n * 512 + slot * 16) = *(const i32x4*)(srcp + i * 8);
    }
  }
  __syncthreads();
  f32x4 yacc[4][4];
  #pragma unroll
  for (int m = 0; m < 4; ++m)
    #pragma unroll
    for (int ct = 0; ct < 4; ++ct) yacc[m][ct] = f32x4{0.f, 0.f, 0.f, 0.f};

  for (int hp = 0; hp < 2; ++hp) {
    const int h = hp * 4 + w;
    f32x4 qacc[4][4];
    #pragma unroll
    for (int mt = 0; mt < 4; ++mt)
      #pragma unroll
      for (int ct = 0; ct < 4; ++ct) qacc[mt][ct] = f32x4{0.f, 0.f, 0.f, 0.f};
    #pragma unroll 2
    for (int ks = 0; ks < 8; ++ks) {
      B16 bfr[4];
      #pragma unroll
      for (int ct = 0; ct < 4; ++ct) {
        const int n = ct * 16 + l15;
        const int slot = (ks * 4 + l4) ^ (n & 31);
        bfr[ct].i = *(const i32x4*)((const char*)xt + n * 512 + slot * 16);
      }
      #pragma unroll
      for (int mt = 0; mt < 4; ++mt) {
        B16 af;
        af.i = *(const i32x4*)(wq_bf + (size_t)(h * 64 + mt * 16 + l15) * 256 + ks * 32 + l4 * 8);
        #pragma unroll
        for (int ct = 0; ct < 4; ++ct)
          qacc[mt][ct] = __builtin_amdgcn_mfma_f32_16x16x32_bf16(af.v, bfr[ct].v, qacc[mt][ct], 0, 0, 0);
      }
    }
    #pragma unroll
    for (int ct = 0; ct < 4; ++ct) {
      float sv[4][4]; float mx = -1e30f;
      #pragma unroll
      for (int mt = 0; mt < 4; ++mt)
        #pragma unroll
        for (int r = 0; r < 4; ++r) {
          sv[mt][r] = qacc[mt][ct][r] * QSCALE;
          mx = fmaxf(mx, sv[mt][r]);
        }
      mx = fmaxf(mx, __shfl_xor(mx, 16)); mx = fmaxf(mx, __shfl_xor(mx, 32));
      float ssum = 0.f;
      #pragma unroll
      for (int mt = 0; mt < 4; ++mt)
        #pragma unroll
        for (int r = 0; r < 4; ++r) { sv[mt][r] = __expf(sv[mt][r] - mx); ssum += sv[mt][r]; }
      ssum += __shfl_xor(ssum, 16); ssum += __shfl_xor(ssum, 32);
      const float inv = 1.f / ssum;
      const int n = ct * 16 + l15;
      #pragma unroll
      for (int mt = 0; mt < 4; ++mt)
        #pragma unroll
        for (int rp = 0; rp < 2; ++rp) {
          const uint pk = packbf2(sv[mt][2 * rp] * inv, sv[mt][2 * rp + 1] * inv);
          const int hd = w * 64 + mt * 16 + l4 * 4 + 2 * rp;
          *(uint*)((char*)PT + ((n * 512 + hd * 2) ^ ((n & 31) << 4))) = pk;
        }
    }
    __syncthreads();
    #pragma unroll 2
    for (int ks = 0; ks < 8; ++ks) {
      B16 bfr[4];
      #pragma unroll
      for (int ct = 0; ct < 4; ++ct) {
        const int n = ct * 16 + l15;
        const int slot = (ks * 4 + l4) ^ (n & 31);
        bfr[ct].i = *(const i32x4*)((const char*)PT + n * 512 + slot * 16);
      }
      #pragma unroll
      for (int m = 0; m < 4; ++m) {
        B16 af;
        af.i = *(const i32x4*)(weff_bf + ((size_t)b * 256 + w * 64 + m * 16 + l15) * 512
                               + hp * 256 + ks * 32 + l4 * 8);
        #pragma unroll
        for (int ct = 0; ct < 4; ++ct)
          yacc[m][ct] = __builtin_amdgcn_mfma_f32_16x16x32_bf16(af.v, bfr[ct].v, yacc[m][ct], 0, 0, 0);
      }
    }
    __syncthreads();
  }
  float sg[2] = {0.f, 0.f}, qg[2] = {0.f, 0.f};
  #pragma unroll
  for (int m = 0; m < 4; ++m) {
    const int o = w * 64 + m * 16 + l4 * 4;
    const f32x4 bv = *(const f32x4*)(bo + o);
    const int gi = m >> 1;
    #pragma unroll
    for (int ct = 0; ct < 4; ++ct)
      #pragma unroll
      for (int r = 0; r < 4; ++r) {
        const float val = yacc[m][ct][r] + bv[r];
        yacc[m][ct][r] = val;
        sg[gi] += val; qg[gi] += val * val;
      }
  }
  #pragma unroll
  for (int msk = 1; msk <= 32; msk <<= 1) {
    sg[0] += __shfl_xor(sg[0], msk); sg[1] += __shfl_xor(sg[1], msk);
    qg[0] += __shfl_xor(qg[0], msk); qg[1] += __shfl_xor(qg[1], msk);
  }
  if (lane == 0) { rsum[w][0] = sg[0]; rsum[w][1] = sg[1]; rsq[w][0] = qg[0]; rsq[w][1] = qg[1]; }
  __syncthreads();
  if (t < 8) {
    atomicAdd(&ws[GSUM_OFF + b * 16 + t], rsum[t >> 1][t & 1]);
    atomicAdd(&ws[GSQ_OFF + b * 16 + t], rsq[t >> 1][t & 1]);
  }
  #pragma unroll
  for (int m = 0; m < 4; ++m)
    #pragma unroll
    for (int ct = 0; ct < 4; ++ct)
      #pragma unroll
      for (int r = 0; r < 4; ++r)
        outp[((size_t)(b * 512) + w * 64 + m * 16 + l4 * 4 + r) * NN + n0 + ct * 16 + l15]
            = yacc[m][ct][r];
}

// ---------------------------------------------------------------------------
// k3: GroupNorm finalize (unchanged)
// ---------------------------------------------------------------------------
__global__ __launch_bounds__(256) void k3_groupnorm(
    const float* __restrict__ x, const float* __restrict__ gamma,
    const float* __restrict__ beta, const float* __restrict__ ws,
    float* out) {
  const int t = threadIdx.x;
  const int b = blockIdx.z, ch = blockIdx.y;
  const int n0 = blockIdx.x * 1024 + t * 4;
  const int g = ch >> 5;
  const float s = ws[GSUM_OFF + b * 16 + g];
  const float s2 = ws[GSQ_OFF + b * 16 + g];
  const float mean = s / GRPN;
  const float var = s2 / GRPN - mean * mean;
  const float inv = rsqrtf(var + EPSV);
  const float ga = gamma[ch] * inv;
  const float be = beta[ch] - mean * ga;
  float* op = out + ((size_t)(b * 512) + ch) * NN + n0;
  float4 v;
  if (ch < 256) v = *(const float4*)op;
  else v = *(const float4*)(x + ((size_t)(b * 256) + (ch - 256)) * NN + n0);
  v.x = v.x * ga + be;
  v.y = v.y * ga + be;
  v.z = v.z * ga + be;
  v.w = v.w * ga + be;
  *(float4*)op = v;
}

extern "C" void kernel_launch(void* const* d_in, const int* in_sizes, int n_in,
                              void* d_out, int out_size, void* d_ws, size_t ws_size,
                              hipStream_t stream) {
  const float* x     = (const float*)d_in[0];
  const float* wq    = (const float*)d_in[1];
  const float* wkv   = (const float*)d_in[2];
  const float* wo    = (const float*)d_in[3];
  const float* bo    = (const float*)d_in[4];
  const float* gamma = (const float*)d_in[5];
  const float* beta  = (const float*)d_in[6];
  float* out = (float*)d_out;
  float* ws = (float*)d_ws;

  // scratch carved from d_out ch256-511 regions (k3 overwrites them last)
  float* spare0 = out + (size_t)256 * NN;
  ushort* wq_bf   = (ushort*)(spare0 + 2097152);   // after xT[0]
  ushort* wkv_bf  = wq_bf + 131072;
  ushort* wo_bf   = wkv_bf + 262144;
  ushort* weff_bf = wo_bf + 131072;
  float*  ksump   = (float*)(weff_bf + 524288);            // 65536 floats
  float*  ctxpA   = out + (size_t)(2 * 512 + 256) * NN + 2097152;  // b2 free, 2097152 f
  float*  ctxpB   = out + (size_t)(3 * 512 + 256) * NN + 2097152;  // b3 free, 2097152 f

  hipMemsetAsync(ws, 0, WS_ZERO_FLOATS * sizeof(float), stream);
  k_cvt<<<128, 256, 0, stream>>>(wq,  wq_bf,  131072);
  k_cvt<<<256, 256, 0, stream>>>(wkv, wkv_bf, 262144);
  k_cvt<<<128, 256, 0, stream>>>(wo,  wo_bf,  131072);
  k0_xprep<<<dim3(256, 8, 4), 256, 0, stream>>>(x, out, ws);
  k1_kvctx<<<dim3(32, 2, 4), 512, 0, stream>>>(out, wkv_bf, ctxpA, ctxpB, ksump);
  k1b_weff<<<dim3(8, 4), 256, 0, stream>>>(ctxpA, ctxpB, ksump, wo_bf, weff_bf);
  k2_qy<<<dim3(256, 4), 256, 0, stream>>>(out, wq_bf, weff_bf, bo, ws);
  k3_groupnorm<<<dim3(16, 512, 4), 256, 0, stream>>>(x, gamma, beta, ws, out);
}